// Round 35
// baseline (5739.272 us; speedup 1.0000x reference)
//
#include <hip/hip_runtime.h>

#define LOG2E 1.44269504088896340736f

__device__ __forceinline__ float lrelu(float z) { return fmaxf(z, 0.01f * z); }
__device__ __forceinline__ float sigf(float z) {
    float p = __builtin_amdgcn_exp2f(-LOG2E * z);
    return __builtin_amdgcn_rcpf(1.0f + p);
}

#define WQ(i) __int_as_float(__builtin_amdgcn_readlane(__float_as_int(wreg[(i) >> 6]), (i) & 63))

__device__ __forceinline__ void lds_barrier() {
    asm volatile("s_waitcnt lgkmcnt(0)" ::: "memory");
    __builtin_amdgcn_s_barrier();
}

// ====== PC-v14: pc8 structure in 128-thread blocks (1 F-wave + 1 X-wave) ====
// R28 diagnosis: pipes half-idle IN ALTERNATION (4 barrier-locked waves march
// into LDS bursts together). R29's intra-block stagger failed (barrier forces
// reconvergence). This round: halve the lockstep group. 512 blocks of 128
// threads = 2 independent blocks/CU sharing NO barrier -> phases drift
// naturally; block 0's LDS burst overlaps block 1's VALU phase. Same total
// waves/work/LDS traffic; weights duplicated per block (7.1KB x2, trivial);
// barrier scope halves. Per-wave body byte-identical to pc8/pc13.
__global__ void __launch_bounds__(128, 2)
pc14_kernel(const float* __restrict__ w,
            const float* __restrict__ Wh1, const float* __restrict__ bh1,
            const float* __restrict__ Wh2, const float* __restrict__ bh2,
            const float* __restrict__ Wh3, const float* __restrict__ bh3,
            const float* __restrict__ Wx1, const float* __restrict__ bx1,
            const float* __restrict__ Wx2, const float* __restrict__ bx2,
            const float* __restrict__ Wx3, const float* __restrict__ bx3,
            float2* __restrict__ out, int B, int T)
{
    __shared__ float4 sW2h[185];       // Wh2 rows 0..36
    __shared__ float4 sW2x[195];       // Wx2 rows 0..38
    __shared__ float2 hbuf[2][128];    // double-buffered h handoff

    {
        float* a = (float*)sW2h;
        for (int i = threadIdx.x; i < 740; i += 128) a[i] = Wh2[i];
        float* b = (float*)sW2x;
        for (int i = threadIdx.x; i < 780; i += 128) b[i] = Wx2[i];
    }

    const int wid  = threadIdx.x >> 6;     // 0..1
    const int lane = threadIdx.x & 63;
    const bool is_f = (wid == 0);

    float wreg[6];
    float wv[140];   // partial VGPR pin (R25 mechanism)
    if (is_f) {
#pragma unroll
        for (int r = 0; r < 6; ++r) {
            const int idx = r * 64 + lane;
            float v = 0.f;
            if      (idx < 100) v = Wh1[idx];
            else if (idx < 150) v = bh1[idx - 100];
            else if (idx < 270) v = Wh2[880 + (idx - 150)];   // rows 44..49
            else if (idx < 290) v = bh2[idx - 270];
            else if (idx < 330) v = Wh3[idx - 290];
            else if (idx < 332) v = bh3[idx - 330];
            wreg[r] = v;
        }
#pragma unroll
        for (int i = 0; i < 140; ++i) {        // pin Wh2 rows 37..43
            wv[i] = Wh2[740 + i];
            asm volatile("" : "+v"(wv[i]));
        }
    } else {
#pragma unroll
        for (int r = 0; r < 6; ++r) {
            const int idx = r * 64 + lane;
            float v = 0.f;
            if      (idx < 100) v = Wx1[idx];
            else if (idx < 150) v = bx1[idx - 100];
            else if (idx < 230) v = Wx2[920 + (idx - 150)];   // rows 46..49
            else if (idx < 250) v = bx2[idx - 230];
            else if (idx < 290) v = Wx3[idx - 250];
            else if (idx < 292) v = bx3[idx - 290];
            wreg[r] = v;
        }
#pragma unroll
        for (int i = 0; i < 140; ++i) {        // pin Wx2 rows 39..45
            wv[i] = Wx2[780 + i];
            asm volatile("" : "+v"(wv[i]));
        }
    }
    __syncthreads();   // startup barrier: full drain (global loads done)

    const int lpA = lane;
    const int lpB = lane + 64;
    const int pA  = blockIdx.x * 128 + lpA;
    const int pB  = blockIdx.x * 128 + lpB;

    float hA0 = 0.f, hA1 = 0.f, hB0 = 0.f, hB1 = 0.f;
    if (is_f) {
        hA0 = w[2 * pA]; hA1 = w[2 * pA + 1];
        hB0 = w[2 * pB]; hB1 = w[2 * pB + 1];
    }
    float2* __restrict__ orowA = out + (size_t)pA * (size_t)T;
    float2* __restrict__ orowB = out + (size_t)pB * (size_t)T;

    for (int t = 0; t <= T; ++t) {
        if (is_f) {
            if (t < T) {
                // ===== F: h = lrelu3(h), 2 points, broadcasts shared =====
                float a1A[50], a1B[50];
#pragma unroll
                for (int j = 0; j < 50; ++j) {
                    const float s0 = WQ(j), s1 = WQ(50 + j), sb = WQ(100 + j);
                    a1A[j] = lrelu(fmaf(hA0, s0, fmaf(hA1, s1, sb)));
                    a1B[j] = lrelu(fmaf(hB0, s0, fmaf(hB1, s1, sb)));
                }
                float accA[20], accB[20];
#pragma unroll
                for (int c = 0; c < 20; ++c) {
                    const float bv = WQ(270 + c);
                    accA[c] = bv; accB[c] = bv;
                }
#pragma unroll
                for (int k = 0; k < 37; ++k) {          // rows 0..36 via LDS
                    const float akA = a1A[k], akB = a1B[k];
#pragma unroll
                    for (int c = 0; c < 5; ++c) {
                        const float4 v = sW2h[k * 5 + c];
                        accA[4*c+0] = fmaf(akA, v.x, accA[4*c+0]);
                        accA[4*c+1] = fmaf(akA, v.y, accA[4*c+1]);
                        accA[4*c+2] = fmaf(akA, v.z, accA[4*c+2]);
                        accA[4*c+3] = fmaf(akA, v.w, accA[4*c+3]);
                        accB[4*c+0] = fmaf(akB, v.x, accB[4*c+0]);
                        accB[4*c+1] = fmaf(akB, v.y, accB[4*c+1]);
                        accB[4*c+2] = fmaf(akB, v.z, accB[4*c+2]);
                        accB[4*c+3] = fmaf(akB, v.w, accB[4*c+3]);
                    }
                }
#pragma unroll
                for (int k = 37; k < 44; ++k) {         // rows 37..43 via pin
                    const float akA = a1A[k], akB = a1B[k];
#pragma unroll
                    for (int c = 0; c < 20; ++c) {
                        const float wvv = wv[(k - 37) * 20 + c];
                        accA[c] = fmaf(akA, wvv, accA[c]);
                        accB[c] = fmaf(akB, wvv, accB[c]);
                    }
                }
#pragma unroll
                for (int k = 44; k < 50; ++k) {         // rows 44..49 via RL
                    const float akA = a1A[k], akB = a1B[k];
#pragma unroll
                    for (int c = 0; c < 20; ++c) {
                        const float wvv = WQ(150 + (k - 44) * 20 + c);
                        accA[c] = fmaf(akA, wvv, accA[c]);
                        accB[c] = fmaf(akB, wvv, accB[c]);
                    }
                }
                float zA0 = WQ(330), zA1 = WQ(331);
                float zB0 = zA0, zB1 = zA1;
#pragma unroll
                for (int k = 0; k < 20; ++k) {
                    const float wx = WQ(290 + 2 * k), wy = WQ(291 + 2 * k);
                    const float eA = lrelu(accA[k]), eB = lrelu(accB[k]);
                    zA0 = fmaf(eA, wx, zA0); zA1 = fmaf(eA, wy, zA1);
                    zB0 = fmaf(eB, wx, zB0); zB1 = fmaf(eB, wy, zB1);
                }
                hA0 = lrelu(zA0); hA1 = lrelu(zA1);
                hB0 = lrelu(zB0); hB1 = lrelu(zB1);

                hbuf[t & 1][lpA] = make_float2(hA0, hA1);
                hbuf[t & 1][lpB] = make_float2(hB0, hB1);
            }
        } else {
            if (t > 0) {
                // ===== X: x_s = sig3(h_s), s = t-1, 2 points =====
                const int s = t - 1;
                const float2 hvA = hbuf[s & 1][lpA];
                const float2 hvB = hbuf[s & 1][lpB];

                float accA[20], accB[20];
#pragma unroll
                for (int c = 0; c < 20; ++c) {
                    const float bv = WQ(230 + c);
                    accA[c] = bv; accB[c] = bv;
                }
#pragma unroll
                for (int k = 0; k < 50; ++k) {
                    const float s0 = WQ(k), s1 = WQ(50 + k), sb = WQ(100 + k);
                    const float xkA = sigf(fmaf(hvA.x, s0, fmaf(hvA.y, s1, sb)));
                    const float xkB = sigf(fmaf(hvB.x, s0, fmaf(hvB.y, s1, sb)));
                    if (k < 39) {                        // rows 0..38 via LDS
#pragma unroll
                        for (int c = 0; c < 5; ++c) {
                            const float4 v = sW2x[k * 5 + c];
                            accA[4*c+0] = fmaf(xkA, v.x, accA[4*c+0]);
                            accA[4*c+1] = fmaf(xkA, v.y, accA[4*c+1]);
                            accA[4*c+2] = fmaf(xkA, v.z, accA[4*c+2]);
                            accA[4*c+3] = fmaf(xkA, v.w, accA[4*c+3]);
                            accB[4*c+0] = fmaf(xkB, v.x, accB[4*c+0]);
                            accB[4*c+1] = fmaf(xkB, v.y, accB[4*c+1]);
                            accB[4*c+2] = fmaf(xkB, v.z, accB[4*c+2]);
                            accB[4*c+3] = fmaf(xkB, v.w, accB[4*c+3]);
                        }
                    } else if (k < 46) {                 // rows 39..45 via pin
#pragma unroll
                        for (int c = 0; c < 20; ++c) {
                            const float wvv = wv[(k - 39) * 20 + c];
                            accA[c] = fmaf(xkA, wvv, accA[c]);
                            accB[c] = fmaf(xkB, wvv, accB[c]);
                        }
                    } else {                             // rows 46..49 via RL
#pragma unroll
                        for (int c = 0; c < 20; ++c) {
                            const float wvv = WQ(150 + (k - 46) * 20 + c);
                            accA[c] = fmaf(xkA, wvv, accA[c]);
                            accB[c] = fmaf(xkB, wvv, accB[c]);
                        }
                    }
                }
                float zA0 = WQ(290), zA1 = WQ(291);
                float zB0 = zA0, zB1 = zA1;
#pragma unroll
                for (int k = 0; k < 20; ++k) {
                    const float wx = WQ(250 + 2 * k), wy = WQ(251 + 2 * k);
                    const float eA = sigf(accA[k]), eB = sigf(accB[k]);
                    zA0 = fmaf(eA, wx, zA0); zA1 = fmaf(eA, wy, zA1);
                    zB0 = fmaf(eB, wx, zB0); zB1 = fmaf(eB, wy, zB1);
                }
                orowA[s] = make_float2(sigf(zA0), sigf(zA1));
                orowB[s] = make_float2(sigf(zB0), sigf(zB1));
            }
        }
        // lgkmcnt-only barrier (R34: equivalent to __syncthreads here)
        lds_barrier();
    }
}

extern "C" void kernel_launch(void* const* d_in, const int* in_sizes, int n_in,
                              void* d_out, int out_size, void* d_ws, size_t ws_size,
                              hipStream_t stream)
{
    const float* w   = (const float*)d_in[0];
    const float* Wh1 = (const float*)d_in[1];
    const float* bh1 = (const float*)d_in[2];
    const float* Wh2 = (const float*)d_in[3];
    const float* bh2 = (const float*)d_in[4];
    const float* Wh3 = (const float*)d_in[5];
    const float* bh3 = (const float*)d_in[6];
    const float* Wx1 = (const float*)d_in[7];
    const float* bx1 = (const float*)d_in[8];
    const float* Wx2 = (const float*)d_in[9];
    const float* bx2 = (const float*)d_in[10];
    const float* Wx3 = (const float*)d_in[11];
    const float* bx3 = (const float*)d_in[12];

    const int B = in_sizes[0] / 2;        // 65536 (divisible by 128)
    const int T = out_size / (B * 2);     // 512

    // 128 threads/block: wave 0 = F, wave 1 = X; 512 blocks = 2/CU, unsynced.
    pc14_kernel<<<B / 128, 128, 0, stream>>>(
        w, Wh1, bh1, Wh2, bh2, Wh3, bh3,
        Wx1, bx1, Wx2, bx2, Wx3, bx3,
        (float2*)d_out, B, T);
}

// Round 36
// 3533.955 us; speedup vs baseline: 1.6240x; 1.6240x over previous
//
#include <hip/hip_runtime.h>

#define LOG2E 1.44269504088896340736f

__device__ __forceinline__ float lrelu(float z) { return fmaxf(z, 0.01f * z); }
__device__ __forceinline__ float sigf(float z) {
    float p = __builtin_amdgcn_exp2f(-LOG2E * z);
    return __builtin_amdgcn_rcpf(1.0f + p);
}

#define WQ(i) __int_as_float(__builtin_amdgcn_readlane(__float_as_int(wreg[(i) >> 6]), (i) & 63))

// ====== PC-v8 (FINAL, converged over R10-R35): 3.53 ms measured ======
// Producer-consumer: 2 F-waves (recurrence) + 2 X-waves (output map, one step
// behind via double-buffered LDS handoff), 2 points/thread, broadcasts shared.
// Broadcast mix per wave: LDS uniform ds_read_b128 (W2 bulk) + partial VGPR
// pin (140 floats, asm "+v") + readlane remainder. Refuted alternatives:
// stagger (R29), X-batching (R30/R32 spill), pk-fma (R31 scalarized), SGB
// prefetch (R23 honored-null), vmcnt-free barrier (R34 null), 128-thr split
// (R35 -63%), occupancy raises (R15/17/18), AGPR/big pins (R24/26 spill).
__global__ void __launch_bounds__(256, 1)
pc8_kernel(const float* __restrict__ w,
           const float* __restrict__ Wh1, const float* __restrict__ bh1,
           const float* __restrict__ Wh2, const float* __restrict__ bh2,
           const float* __restrict__ Wh3, const float* __restrict__ bh3,
           const float* __restrict__ Wx1, const float* __restrict__ bx1,
           const float* __restrict__ Wx2, const float* __restrict__ bx2,
           const float* __restrict__ Wx3, const float* __restrict__ bx3,
           float2* __restrict__ out, int B, int T)
{
    __shared__ float4 sW2h[185];       // Wh2 rows 0..36
    __shared__ float4 sW2x[195];       // Wx2 rows 0..38
    __shared__ float2 hbuf[2][256];    // double-buffered h handoff

    {
        float* a = (float*)sW2h;
        for (int i = threadIdx.x; i < 740; i += 256) a[i] = Wh2[i];
        float* b = (float*)sW2x;
        for (int i = threadIdx.x; i < 780; i += 256) b[i] = Wx2[i];
    }

    const int wid  = threadIdx.x >> 6;     // 0..3
    const int lane = threadIdx.x & 63;
    const bool is_f = (wid < 2);

    float wreg[6];
    float wv[140];   // partial VGPR pin (R25 mechanism)
    if (is_f) {
#pragma unroll
        for (int r = 0; r < 6; ++r) {
            const int idx = r * 64 + lane;
            float v = 0.f;
            if      (idx < 100) v = Wh1[idx];
            else if (idx < 150) v = bh1[idx - 100];
            else if (idx < 270) v = Wh2[880 + (idx - 150)];   // rows 44..49
            else if (idx < 290) v = bh2[idx - 270];
            else if (idx < 330) v = Wh3[idx - 290];
            else if (idx < 332) v = bh3[idx - 330];
            wreg[r] = v;
        }
#pragma unroll
        for (int i = 0; i < 140; ++i) {        // pin Wh2 rows 37..43
            wv[i] = Wh2[740 + i];
            asm volatile("" : "+v"(wv[i]));
        }
    } else {
#pragma unroll
        for (int r = 0; r < 6; ++r) {
            const int idx = r * 64 + lane;
            float v = 0.f;
            if      (idx < 100) v = Wx1[idx];
            else if (idx < 150) v = bx1[idx - 100];
            else if (idx < 230) v = Wx2[920 + (idx - 150)];   // rows 46..49
            else if (idx < 250) v = bx2[idx - 230];
            else if (idx < 290) v = Wx3[idx - 250];
            else if (idx < 292) v = bx3[idx - 290];
            wreg[r] = v;
        }
#pragma unroll
        for (int i = 0; i < 140; ++i) {        // pin Wx2 rows 39..45
            wv[i] = Wx2[780 + i];
            asm volatile("" : "+v"(wv[i]));
        }
    }
    __syncthreads();

    const int lw = is_f ? wid : (wid - 2);
    const int lpA = lw * 128 + lane;
    const int lpB = lpA + 64;
    const int pA  = blockIdx.x * 256 + lpA;
    const int pB  = blockIdx.x * 256 + lpB;

    float hA0 = 0.f, hA1 = 0.f, hB0 = 0.f, hB1 = 0.f;
    if (is_f) {
        hA0 = w[2 * pA]; hA1 = w[2 * pA + 1];
        hB0 = w[2 * pB]; hB1 = w[2 * pB + 1];
    }
    float2* __restrict__ orowA = out + (size_t)pA * (size_t)T;
    float2* __restrict__ orowB = out + (size_t)pB * (size_t)T;

    for (int t = 0; t <= T; ++t) {
        if (is_f) {
            if (t < T) {
                // ===== F: h = lrelu3(h), 2 points, broadcasts shared =====
                float a1A[50], a1B[50];
#pragma unroll
                for (int j = 0; j < 50; ++j) {
                    const float s0 = WQ(j), s1 = WQ(50 + j), sb = WQ(100 + j);
                    a1A[j] = lrelu(fmaf(hA0, s0, fmaf(hA1, s1, sb)));
                    a1B[j] = lrelu(fmaf(hB0, s0, fmaf(hB1, s1, sb)));
                }
                float accA[20], accB[20];
#pragma unroll
                for (int c = 0; c < 20; ++c) {
                    const float bv = WQ(270 + c);
                    accA[c] = bv; accB[c] = bv;
                }
#pragma unroll
                for (int k = 0; k < 37; ++k) {          // rows 0..36 via LDS
                    const float akA = a1A[k], akB = a1B[k];
#pragma unroll
                    for (int c = 0; c < 5; ++c) {
                        const float4 v = sW2h[k * 5 + c];
                        accA[4*c+0] = fmaf(akA, v.x, accA[4*c+0]);
                        accA[4*c+1] = fmaf(akA, v.y, accA[4*c+1]);
                        accA[4*c+2] = fmaf(akA, v.z, accA[4*c+2]);
                        accA[4*c+3] = fmaf(akA, v.w, accA[4*c+3]);
                        accB[4*c+0] = fmaf(akB, v.x, accB[4*c+0]);
                        accB[4*c+1] = fmaf(akB, v.y, accB[4*c+1]);
                        accB[4*c+2] = fmaf(akB, v.z, accB[4*c+2]);
                        accB[4*c+3] = fmaf(akB, v.w, accB[4*c+3]);
                    }
                }
#pragma unroll
                for (int k = 37; k < 44; ++k) {         // rows 37..43 via pin
                    const float akA = a1A[k], akB = a1B[k];
#pragma unroll
                    for (int c = 0; c < 20; ++c) {
                        const float wvv = wv[(k - 37) * 20 + c];
                        accA[c] = fmaf(akA, wvv, accA[c]);
                        accB[c] = fmaf(akB, wvv, accB[c]);
                    }
                }
#pragma unroll
                for (int k = 44; k < 50; ++k) {         // rows 44..49 via RL
                    const float akA = a1A[k], akB = a1B[k];
#pragma unroll
                    for (int c = 0; c < 20; ++c) {
                        const float wvv = WQ(150 + (k - 44) * 20 + c);
                        accA[c] = fmaf(akA, wvv, accA[c]);
                        accB[c] = fmaf(akB, wvv, accB[c]);
                    }
                }
                float zA0 = WQ(330), zA1 = WQ(331);
                float zB0 = zA0, zB1 = zA1;
#pragma unroll
                for (int k = 0; k < 20; ++k) {
                    const float wx = WQ(290 + 2 * k), wy = WQ(291 + 2 * k);
                    const float eA = lrelu(accA[k]), eB = lrelu(accB[k]);
                    zA0 = fmaf(eA, wx, zA0); zA1 = fmaf(eA, wy, zA1);
                    zB0 = fmaf(eB, wx, zB0); zB1 = fmaf(eB, wy, zB1);
                }
                hA0 = lrelu(zA0); hA1 = lrelu(zA1);
                hB0 = lrelu(zB0); hB1 = lrelu(zB1);

                hbuf[t & 1][lpA] = make_float2(hA0, hA1);
                hbuf[t & 1][lpB] = make_float2(hB0, hB1);
            }
        } else {
            if (t > 0) {
                // ===== X: x_s = sig3(h_s), s = t-1, 2 points =====
                const int s = t - 1;
                const float2 hvA = hbuf[s & 1][lpA];
                const float2 hvB = hbuf[s & 1][lpB];

                float accA[20], accB[20];
#pragma unroll
                for (int c = 0; c < 20; ++c) {
                    const float bv = WQ(230 + c);
                    accA[c] = bv; accB[c] = bv;
                }
#pragma unroll
                for (int k = 0; k < 50; ++k) {
                    // Wx1-trip via RL (off the binding LDS pipe)
                    const float s0 = WQ(k), s1 = WQ(50 + k), sb = WQ(100 + k);
                    const float xkA = sigf(fmaf(hvA.x, s0, fmaf(hvA.y, s1, sb)));
                    const float xkB = sigf(fmaf(hvB.x, s0, fmaf(hvB.y, s1, sb)));
                    if (k < 39) {                        // rows 0..38 via LDS
#pragma unroll
                        for (int c = 0; c < 5; ++c) {
                            const float4 v = sW2x[k * 5 + c];
                            accA[4*c+0] = fmaf(xkA, v.x, accA[4*c+0]);
                            accA[4*c+1] = fmaf(xkA, v.y, accA[4*c+1]);
                            accA[4*c+2] = fmaf(xkA, v.z, accA[4*c+2]);
                            accA[4*c+3] = fmaf(xkA, v.w, accA[4*c+3]);
                            accB[4*c+0] = fmaf(xkB, v.x, accB[4*c+0]);
                            accB[4*c+1] = fmaf(xkB, v.y, accB[4*c+1]);
                            accB[4*c+2] = fmaf(xkB, v.z, accB[4*c+2]);
                            accB[4*c+3] = fmaf(xkB, v.w, accB[4*c+3]);
                        }
                    } else if (k < 46) {                 // rows 39..45 via pin
#pragma unroll
                        for (int c = 0; c < 20; ++c) {
                            const float wvv = wv[(k - 39) * 20 + c];
                            accA[c] = fmaf(xkA, wvv, accA[c]);
                            accB[c] = fmaf(xkB, wvv, accB[c]);
                        }
                    } else {                             // rows 46..49 via RL
#pragma unroll
                        for (int c = 0; c < 20; ++c) {
                            const float wvv = WQ(150 + (k - 46) * 20 + c);
                            accA[c] = fmaf(xkA, wvv, accA[c]);
                            accB[c] = fmaf(xkB, wvv, accB[c]);
                        }
                    }
                }
                float zA0 = WQ(290), zA1 = WQ(291);
                float zB0 = zA0, zB1 = zA1;
#pragma unroll
                for (int k = 0; k < 20; ++k) {
                    const float wx = WQ(250 + 2 * k), wy = WQ(251 + 2 * k);
                    const float eA = sigf(accA[k]), eB = sigf(accB[k]);
                    zA0 = fmaf(eA, wx, zA0); zA1 = fmaf(eA, wy, zA1);
                    zB0 = fmaf(eB, wx, zB0); zB1 = fmaf(eB, wy, zB1);
                }
                orowA[s] = make_float2(sigf(zA0), sigf(zA1));
                orowB[s] = make_float2(sigf(zB0), sigf(zB1));
            }
        }
        __syncthreads();   // orders hbuf write (iter t) -> read (iter t+1)
    }
}

extern "C" void kernel_launch(void* const* d_in, const int* in_sizes, int n_in,
                              void* d_out, int out_size, void* d_ws, size_t ws_size,
                              hipStream_t stream)
{
    const float* w   = (const float*)d_in[0];
    const float* Wh1 = (const float*)d_in[1];
    const float* bh1 = (const float*)d_in[2];
    const float* Wh2 = (const float*)d_in[3];
    const float* bh2 = (const float*)d_in[4];
    const float* Wh3 = (const float*)d_in[5];
    const float* bh3 = (const float*)d_in[6];
    const float* Wx1 = (const float*)d_in[7];
    const float* bx1 = (const float*)d_in[8];
    const float* Wx2 = (const float*)d_in[9];
    const float* bx2 = (const float*)d_in[10];
    const float* Wx3 = (const float*)d_in[11];
    const float* bx3 = (const float*)d_in[12];

    const int B = in_sizes[0] / 2;        // 65536 (divisible by 256)
    const int T = out_size / (B * 2);     // 512

    pc8_kernel<<<B / 256, 256, 0, stream>>>(
        w, Wh1, bh1, Wh2, bh2, Wh3, bh3,
        Wx1, bx1, Wx2, bx2, Wx3, bx3,
        (float2*)d_out, B, T);
}